// Round 1
// baseline (248.295 us; speedup 1.0000x reference)
//
#include <hip/hip_runtime.h>
#include <math.h>

// ---------------- problem constants ----------------
#define TARGET_SCALE 0.06f
constexpr int N_ = 8, S_ = 2048, C_ = 4, V_ = 128, K_ = 512;
constexpr int NS = N_ * S_;       // 16384 (n,s) pairs
constexpr int NQ = NS * C_;       // 65536 queries

// output layout (floats, concatenated in reference return order)
constexpr int O_DISC = 0;                  // [N,S,C,V] = 8388608
constexpr int O_IDX  = NQ * V_;            // 8388608, [N,S,C]
constexpr int O_VQ   = O_IDX + NQ;         // 8454144
constexpr int O_ENC  = O_VQ + NQ;          // 8519680
constexpr int O_ENT  = O_ENC + NQ;         // 8585216 (scalar)

// workspace layout (floats)
constexpr int WS_EMB  = 0;                 // normalized emb, C*K*V = 262144
constexpr int WS_E2   = C_ * K_ * V_;      // e2 per code, C*K = 2048
constexpr int WS_HIST = WS_E2 + C_ * K_;   // 512 bins

// ---------------- tiling ----------------
constexpr int QB  = 64;    // queries (n,s) per tile
constexpr int KC  = 64;    // codes per LDS chunk
constexpr int XSP = 132;   // padded X row (floats): 132*4B, stride%32 = 4 -> conflict-free
constexpr int ESP = 68;    // padded E row (floats): 68*4B, 2-way max aliasing (free)

// =====================================================================
// Kernel 1: normalize embeddings, e2, zero histogram
// =====================================================================
__global__ __launch_bounds__(256) void prep_emb(const float* __restrict__ emb0,
                                                float* __restrict__ ws) {
    const int wave = threadIdx.x >> 6;
    const int lane = threadIdx.x & 63;
    const int row  = blockIdx.x * 4 + wave;            // 0..2047 = c*512+k
    const float tn = TARGET_SCALE * sqrtf((float)V_);

    float2 e = *(const float2*)(emb0 + row * V_ + lane * 2);
    float ss = e.x * e.x + e.y * e.y;
    #pragma unroll
    for (int off = 32; off; off >>= 1) ss += __shfl_xor(ss, off);
    const float nrm = sqrtf(ss);

    float2 en;
    en.x = (tn * e.x) / nrm;    // mimic reference elementwise mul-then-div
    en.y = (tn * e.y) / nrm;
    *(float2*)(ws + WS_EMB + row * V_ + lane * 2) = en;

    float s2 = en.x * en.x + en.y * en.y;
    #pragma unroll
    for (int off = 32; off; off >>= 1) s2 += __shfl_xor(s2, off);
    if (lane == 0) ws[WS_E2 + row] = s2;

    if (blockIdx.x == 0) {   // zero histogram (ws is poisoned every launch)
        ws[WS_HIST + threadIdx.x]       = 0.f;
        ws[WS_HIST + 256 + threadIdx.x] = 0.f;
    }
}

// =====================================================================
// Kernel 2: distances + argmin + all per-query outputs
// block: 256 threads = 16 qg x 16 kg; thread tile 4q x 4k
// =====================================================================
__global__ __launch_bounds__(256) void vq_main(const float* __restrict__ x0,
                                               float* __restrict__ ws,
                                               float* __restrict__ out) {
    __shared__ float XS[QB * XSP];     // raw x0 rows (33792 B)
    __shared__ float ES[KC * ESP];     // normalized code chunk (17408 B)
    __shared__ float s_scale[QB];
    __shared__ float s_x2[QB];
    __shared__ float s_es2[KC];
    __shared__ int   s_bestk[QB];

    const int c   = blockIdx.y;
    const int tid = threadIdx.x;
    const int qg  = tid >> 4;          // 0..15
    const int kg  = tid & 15;          // 0..15
    const float tn = TARGET_SCALE * sqrtf((float)V_);

    const float* __restrict__ embc = ws + WS_EMB + c * K_ * V_;
    const float* __restrict__ e2c  = ws + WS_E2 + c * K_;
    float* __restrict__ hist = ws + WS_HIST;

    for (int tile = blockIdx.x; tile < NS / QB; tile += gridDim.x) {
        const int nsBase = tile * QB;

        __syncthreads();   // previous tile's epilogue done with XS/s_*
        // ---- stage x0 rows: 64 x 128 floats, coalesced f4 ----
        #pragma unroll
        for (int it = 0; it < 8; ++it) {
            int fi  = tid + 256 * it;             // 0..2047 f4 slots
            int row = fi >> 5, u4 = fi & 31;
            float4 v = *(const float4*)(x0 + ((nsBase + row) * C_ + c) * V_ + u4 * 4);
            *(float4*)(XS + row * XSP + u4 * 4) = v;
        }
        __syncthreads();

        // ---- per-row norm -> scale; then x2 = sum((scale*x0)^2) ----
        {
            const int row = tid >> 2, j = tid & 3;
            const float4* xr4 = (const float4*)(XS + row * XSP + j * 32);
            float ss = 0.f;
            #pragma unroll
            for (int m = 0; m < 8; ++m) {
                float4 v = xr4[m];
                ss += v.x * v.x + v.y * v.y + v.z * v.z + v.w * v.w;
            }
            ss += __shfl_xor(ss, 1);
            ss += __shfl_xor(ss, 2);
            const float scale = tn / sqrtf(ss);
            float x2 = 0.f;
            #pragma unroll
            for (int m = 0; m < 8; ++m) {
                float4 v = xr4[m];
                float a = scale * v.x, b = scale * v.y, d = scale * v.z, e = scale * v.w;
                x2 += a * a + b * b + d * d + e * e;
            }
            x2 += __shfl_xor(x2, 1);
            x2 += __shfl_xor(x2, 2);
            if (j == 0) { s_scale[row] = scale; s_x2[row] = x2; }
        }
        __syncthreads();

        // ---- K-chunk loop: running per-thread argmin ----
        float bd[4]; int bk[4];
        #pragma unroll
        for (int qq = 0; qq < 4; ++qq) { bd[qq] = 3.4e38f; bk[qq] = 0x7fffffff; }

        for (int kc = 0; kc < K_ / KC; ++kc) {
            float acc[4][4] = {{0.f}};
            for (int vh = 0; vh < 2; ++vh) {
                __syncthreads();   // everyone done reading previous ES
                // stage 64 codes x 64 v, coalesced f4
                #pragma unroll
                for (int it = 0; it < 4; ++it) {
                    int fi = tid + 256 * it;          // 0..1023
                    int r = fi >> 4, u4 = fi & 15;
                    float4 v = *(const float4*)(embc + (kc * KC + r) * V_ + vh * 64 + u4 * 4);
                    *(float4*)(ES + r * ESP + u4 * 4) = v;
                }
                if (vh == 0 && tid < KC) s_es2[tid] = e2c[kc * KC + tid];
                __syncthreads();

                #pragma unroll
                for (int vq = 0; vq < 16; ++vq) {
                    float4 xv[4], ev[4];
                    #pragma unroll
                    for (int qq = 0; qq < 4; ++qq)
                        xv[qq] = *(const float4*)(XS + (qg + 16 * qq) * XSP + vh * 64 + vq * 4);
                    #pragma unroll
                    for (int kk = 0; kk < 4; ++kk)
                        ev[kk] = *(const float4*)(ES + (kg + 16 * kk) * ESP + vq * 4);
                    #pragma unroll
                    for (int qq = 0; qq < 4; ++qq)
                        #pragma unroll
                        for (int kk = 0; kk < 4; ++kk) {
                            acc[qq][kk] = fmaf(xv[qq].x, ev[kk].x, acc[qq][kk]);
                            acc[qq][kk] = fmaf(xv[qq].y, ev[kk].y, acc[qq][kk]);
                            acc[qq][kk] = fmaf(xv[qq].z, ev[kk].z, acc[qq][kk]);
                            acc[qq][kk] = fmaf(xv[qq].w, ev[kk].w, acc[qq][kk]);
                        }
                }
            }
            // d2 = (x2 + e2) - 2*xe ; strict < keeps first (k ascending in kk,kc)
            #pragma unroll
            for (int kk = 0; kk < 4; ++kk) {
                const int kloc  = kg + 16 * kk;
                const float e2v = s_es2[kloc];
                const int kglob = kc * KC + kloc;
                #pragma unroll
                for (int qq = 0; qq < 4; ++qq) {
                    const int ql = qg + 16 * qq;
                    const float xe = s_scale[ql] * acc[qq][kk];
                    const float t  = s_x2[ql] + e2v;
                    const float d  = fmaf(-2.f, xe, t);
                    if (d < bd[qq]) { bd[qq] = d; bk[qq] = kglob; }
                }
            }
        }

        // ---- cross-kg argmin reduce (16 lanes share a qg), tie -> lower k ----
        #pragma unroll
        for (int off = 8; off; off >>= 1) {
            #pragma unroll
            for (int qq = 0; qq < 4; ++qq) {
                float od = __shfl_xor(bd[qq], off);
                int   ok = __shfl_xor(bk[qq], off);
                if (od < bd[qq] || (od == bd[qq] && ok < bk[qq])) { bd[qq] = od; bk[qq] = ok; }
            }
        }
        if (kg == 0) {
            #pragma unroll
            for (int qq = 0; qq < 4; ++qq) s_bestk[qg + 16 * qq] = bk[qq];
        }
        __syncthreads();

        // ---- epilogue: 4 threads per query ----
        {
            const int q = tid >> 2, j = tid & 3;
            const int kstar   = s_bestk[q];
            const float scale = s_scale[q];
            const int qglob   = (nsBase + q) * C_ + c;
            const float* er = embc + kstar * V_ + j * 32;
            const float* xr = XS + q * XSP + j * 32;
            float* dr = out + O_DISC + qglob * V_ + j * 32;
            float vqp = 0.f, en2 = 0.f;
            #pragma unroll
            for (int m = 0; m < 8; ++m) {
                float4 e4 = *(const float4*)(er + m * 4);
                float4 x4 = *(const float4*)(xr + m * 4);
                float xa = scale * x4.x, xb = scale * x4.y, xc = scale * x4.z, xd = scale * x4.w;
                float da = xa - e4.x, db = xb - e4.y, dc = xc - e4.z, dd = xd - e4.w;
                vqp += da * da + db * db + dc * dc + dd * dd;
                float ga = xa - x4.x, gb = xb - x4.y, gc = xc - x4.z, gd = xd - x4.w;
                en2 += ga * ga + gb * gb + gc * gc + gd * gd;
                *(float4*)(dr + m * 4) = e4;   // discrete == chosen code row
            }
            vqp += __shfl_xor(vqp, 1);
            vqp += __shfl_xor(vqp, 2);
            en2 += __shfl_xor(en2, 1);
            en2 += __shfl_xor(en2, 2);
            if (j == 0) {
                out[O_IDX + qglob] = (float)(kstar + c * K_);
                out[O_VQ  + qglob] = vqp;
                out[O_ENC + qglob] = vqp + en2;
                atomicAdd(hist + kstar, 1.0f);
            }
        }
    }
}

// =====================================================================
// Kernel 3: entropy over 512-bin histogram
// =====================================================================
__global__ __launch_bounds__(256) void entropy_k(const float* __restrict__ ws,
                                                 float* __restrict__ out) {
    const float* hist = ws + WS_HIST;
    const int t = threadIdx.x;
    float s = 0.f;
    for (int i = t; i < K_; i += 256) {
        float h = hist[i];
        if (h > 0.f) {
            float p = h / (float)NQ;
            s += p * logf(p);
        }
    }
    #pragma unroll
    for (int off = 32; off; off >>= 1) s += __shfl_xor(s, off);
    __shared__ float wsum[4];
    if ((t & 63) == 0) wsum[t >> 6] = s;
    __syncthreads();
    if (t == 0) out[O_ENT] = -(wsum[0] + wsum[1] + wsum[2] + wsum[3]);
}

// =====================================================================
extern "C" void kernel_launch(void* const* d_in, const int* in_sizes, int n_in,
                              void* d_out, int out_size, void* d_ws, size_t ws_size,
                              hipStream_t stream) {
    const float* x0   = (const float*)d_in[0];
    const float* emb0 = (const float*)d_in[1];
    float* out = (float*)d_out;
    float* ws  = (float*)d_ws;

    prep_emb<<<512, 256, 0, stream>>>(emb0, ws);
    // grid: 128 ns-tiles (x-stride covers 256 tiles -> 2/block, all resident) x 4 codebooks
    vq_main<<<dim3(128, 4), 256, 0, stream>>>(x0, ws, out);
    entropy_k<<<1, 256, 0, stream>>>(ws, out);
}